// Round 1
// baseline (439.738 us; speedup 1.0000x reference)
//
#include <hip/hip_runtime.h>
#include <hip/hip_bf16.h>

#define T_LEN 256
#define B_DIM 128
#define EMB 1024
#define HID 1024
#define NLAB 50
#define M_ROWS (T_LEN * B_DIM)   // 32768
#define N3H 3072

typedef __attribute__((ext_vector_type(8))) short short8;
typedef __attribute__((ext_vector_type(4))) float f32x4;

// ---- helpers ----
static __device__ __forceinline__ ushort f2b(float x) {
    // RNE f32 -> bf16 (finite values only, which holds here)
    unsigned u = __builtin_bit_cast(unsigned, x);
    unsigned lsb = (u >> 16) & 1u;
    u += 0x7fffu + lsb;
    return (ushort)(u >> 16);
}
static __device__ __forceinline__ float b2f(ushort u) {
    unsigned v = ((unsigned)u) << 16;
    return __builtin_bit_cast(float, v);
}
static __device__ __forceinline__ void gload16(const ushort* g, ushort* l) {
    __builtin_amdgcn_global_load_lds(
        (const __attribute__((address_space(1))) unsigned int*)g,
        (__attribute__((address_space(3))) unsigned int*)l,
        16, 0, 0);
}

// ---- kernel 1: x = bf16(emb[sentence])  [32768][1024] ----
__global__ __launch_bounds__(256) void gather_convert(
    const int* __restrict__ sent, const float* __restrict__ emb,
    ushort* __restrict__ xb)
{
    const int r = blockIdx.x;
    const int k4 = threadIdx.x * 4;
    const size_t src = (size_t)sent[r] * EMB + k4;
    float4 v = *(const float4*)(emb + src);
    ushort4 o;
    o.x = f2b(v.x); o.y = f2b(v.y); o.z = f2b(v.z); o.w = f2b(v.w);
    *(ushort4*)(xb + (size_t)r * EMB + k4) = o;
}

// ---- kernel 2: Wt[n][k] = bf16(W[k][n])   [3072][1024] ----
__global__ __launch_bounds__(256) void transposeW(
    const float* __restrict__ W, ushort* __restrict__ Wt)
{
    __shared__ float tile[32][33];
    const int n0 = blockIdx.x * 32, k0 = blockIdx.y * 32;
    const int tx = threadIdx.x, ty = threadIdx.y;   // 32 x 8
#pragma unroll
    for (int j = 0; j < 32; j += 8)
        tile[ty + j][tx] = W[(size_t)(k0 + ty + j) * N3H + n0 + tx];
    __syncthreads();
#pragma unroll
    for (int j = 0; j < 32; j += 8)
        Wt[(size_t)(n0 + ty + j) * EMB + k0 + tx] = f2b(tile[tx][ty + j]);
}

// ---- kernel 3: GEMM [Mx1024]x[1024xN] with fused bias+activation ----
// A: bf16 row-major [M][1024]; Bt: bf16 [Ncols][1024] (transposed W)
// mode 0: grid.y 0..15 -> cols 0..2047; <1024: tanh->outZ, else sigmoid->outF
// mode 1: all sigmoid -> outZ
__global__ __launch_bounds__(256) void gemm_act(
    const ushort* __restrict__ A, const ushort* __restrict__ Bt,
    const float* __restrict__ bias,
    ushort* __restrict__ outZ, ushort* __restrict__ outF, int mode)
{
    __shared__ ushort Als[4 * 128 * 8];   // chunked [kg][row] 16B chunks, 8KB
    __shared__ ushort Bls[4 * 128 * 8];

    const int tid = threadIdx.x;
    const int lane = tid & 63;
    const int w = tid >> 6;
    const int wr = w >> 1, wc = w & 1;
    const int l15 = lane & 15, lh = lane >> 4;
    const int tile_m = blockIdx.x * 128;
    const int n0 = blockIdx.y * 128;

    f32x4 acc[4][4] = {};

    const int s0 = tid, s1 = tid + 256;
    const int kg0 = s0 >> 7, row0 = s0 & 127;
    const int kg1 = s1 >> 7, row1 = s1 & 127;
    const ushort* ga0 = A + (size_t)(tile_m + row0) * EMB + kg0 * 8;
    const ushort* ga1 = A + (size_t)(tile_m + row1) * EMB + kg1 * 8;
    const ushort* gb0 = Bt + (size_t)(n0 + row0) * EMB + kg0 * 8;
    const ushort* gb1 = Bt + (size_t)(n0 + row1) * EMB + kg1 * 8;
    ushort* la0 = &Als[s0 * 8];
    ushort* la1 = &Als[s1 * 8];
    ushort* lb0 = &Bls[s0 * 8];
    ushort* lb1 = &Bls[s1 * 8];

    for (int kk = 0; kk < EMB / 32; ++kk) {
        const int ko = kk * 32;
        gload16(ga0 + ko, la0);
        gload16(ga1 + ko, la1);
        gload16(gb0 + ko, lb0);
        gload16(gb1 + ko, lb1);
        __syncthreads();

        short8 af[4], bfr[4];
#pragma unroll
        for (int i = 0; i < 4; i++) {
            af[i]  = *(const short8*)&Als[(size_t)(lh * 128 + wr * 64 + i * 16 + l15) * 8];
            bfr[i] = *(const short8*)&Bls[(size_t)(lh * 128 + wc * 64 + i * 16 + l15) * 8];
        }
#pragma unroll
        for (int mi = 0; mi < 4; mi++)
#pragma unroll
            for (int ni = 0; ni < 4; ni++)
                acc[mi][ni] = __builtin_amdgcn_mfma_f32_16x16x32_bf16(
                    af[mi], bfr[ni], acc[mi][ni], 0, 0, 0);
        __syncthreads();
    }

    const float* bptr = bias + (size_t)blockIdx.y * 128;
    ushort* dst; int colbase; bool use_tanh;
    if (mode == 0) {
        if (blockIdx.y < 8) { dst = outZ; colbase = blockIdx.y * 128; use_tanh = true; }
        else { dst = outF; colbase = blockIdx.y * 128 - 1024; use_tanh = false; }
    } else {
        dst = outZ; colbase = blockIdx.y * 128; use_tanh = false;
    }

#pragma unroll
    for (int mi = 0; mi < 4; mi++) {
#pragma unroll
        for (int ni = 0; ni < 4; ni++) {
            const int nb = wc * 64 + ni * 16 + l15;
            const float bv = bptr[nb];
            const int rb = tile_m + wr * 64 + mi * 16 + lh * 4;
#pragma unroll
            for (int r = 0; r < 4; r++) {
                float y = acc[mi][ni][r] + bv;
                float a = use_tanh ? tanhf(y) : (1.f / (1.f + expf(-y)));
                dst[(size_t)(rb + r) * HID + colbase + nb] = f2b(a);
            }
        }
    }
}

// ---- kernel 4: fo-pool scan over T; h = o_last * c_last ----
__global__ __launch_bounds__(256) void fo_pool(
    const unsigned* __restrict__ z32, const unsigned* __restrict__ fz32,
    const unsigned* __restrict__ o32, float* __restrict__ hbuf)
{
    const int p = blockIdx.x * 256 + threadIdx.x;  // 0..65535 (pairs of h)
    float c0 = 0.f, c1 = 0.f;
#pragma unroll 4
    for (int t = 0; t < T_LEN; ++t) {
        unsigned zz = z32[(size_t)t * (B_DIM * HID / 2) + p];
        unsigned ff = fz32[(size_t)t * (B_DIM * HID / 2) + p];
        float z0 = b2f((ushort)(zz & 0xffffu)), z1 = b2f((ushort)(zz >> 16));
        float f0 = b2f((ushort)(ff & 0xffffu)), f1 = b2f((ushort)(ff >> 16));
        c0 += f0 * (z0 - c0);   // = f*z + (1-f)*c
        c1 += f1 * (z1 - c1);
    }
    unsigned oo = o32[p];
    float o0 = b2f((ushort)(oo & 0xffffu)), o1 = b2f((ushort)(oo >> 16));
    hbuf[2 * p]     = o0 * c0;
    hbuf[2 * p + 1] = o1 * c1;
}

// ---- kernel 5: logits = h @ Wout + bout; log_softmax ----
__global__ __launch_bounds__(64) void classify(
    const float* __restrict__ hbuf, const float* __restrict__ Wout,
    const float* __restrict__ bout, float* __restrict__ out)
{
    __shared__ float hs[HID];
    const int b = blockIdx.x, l = threadIdx.x;
#pragma unroll
    for (int j = 0; j < HID; j += 64) hs[j + l] = hbuf[(size_t)b * HID + j + l];
    __syncthreads();
    float acc = -1e30f;
    if (l < NLAB) {
        float s = bout[l];
        for (int e = 0; e < HID; e++) s += hs[e] * Wout[(size_t)e * NLAB + l];
        acc = s;
    }
    float m = acc;
#pragma unroll
    for (int off = 32; off; off >>= 1) m = fmaxf(m, __shfl_xor(m, off));
    float ex = (l < NLAB) ? expf(acc - m) : 0.f;
    float sum = ex;
#pragma unroll
    for (int off = 32; off; off >>= 1) sum += __shfl_xor(sum, off);
    if (l < NLAB) out[(size_t)b * NLAB + l] = acc - m - logf(sum);
}

extern "C" void kernel_launch(void* const* d_in, const int* in_sizes, int n_in,
                              void* d_out, int out_size, void* d_ws, size_t ws_size,
                              hipStream_t stream) {
    const int* sent = (const int*)d_in[0];
    const float* emb = (const float*)d_in[1];
    const float* W = (const float*)d_in[2];
    const float* bias = (const float*)d_in[3];
    const float* Wout = (const float*)d_in[4];
    const float* bout = (const float*)d_in[5];
    float* out = (float*)d_out;

    ushort* xb = (ushort*)d_ws;                      // 32768*1024 bf16
    ushort* Wt = xb + (size_t)M_ROWS * EMB;          // 3072*1024 bf16
    ushort* zb = Wt + (size_t)N3H * EMB;             // 32768*1024 bf16
    ushort* fb = zb + (size_t)M_ROWS * HID;          // 32768*1024 bf16
    ushort* ob = fb + (size_t)M_ROWS * HID;          // 128*1024 bf16
    float* hb = (float*)(ob + (size_t)B_DIM * HID);  // 128*1024 f32

    hipLaunchKernelGGL(gather_convert, dim3(M_ROWS), dim3(256), 0, stream,
                       sent, emb, xb);
    hipLaunchKernelGGL(transposeW, dim3(N3H / 32, EMB / 32), dim3(32, 8), 0, stream,
                       W, Wt);
    // main GEMM: z (tanh) and f (sigmoid), cols 0..2047
    hipLaunchKernelGGL(gemm_act, dim3(M_ROWS / 128, 16), dim3(256), 0, stream,
                       xb, Wt, bias, zb, fb, 0);
    // o-gate GEMM: only last timestep rows, cols 2048..3071
    hipLaunchKernelGGL(gemm_act, dim3(1, 8), dim3(256), 0, stream,
                       xb + (size_t)(M_ROWS - B_DIM) * EMB,
                       Wt + (size_t)2048 * EMB, bias + 2048,
                       ob, (ushort*)nullptr, 1);
    hipLaunchKernelGGL(fo_pool, dim3(B_DIM * HID / 2 / 256), dim3(256), 0, stream,
                       (const unsigned*)zb, (const unsigned*)fb,
                       (const unsigned*)ob, hb);
    hipLaunchKernelGGL(classify, dim3(B_DIM), dim3(64), 0, stream,
                       hb, Wout, bout, out);
}